// Round 4
// baseline (109.829 us; speedup 1.0000x reference)
//
#include <hip/hip_runtime.h>
#include <hip/hip_bf16.h>

#define MTOK 16384
#define DDIM 2048
#define NEXP 8
#define RNK 16
#define NC 128          // E*R down-projection columns
#define NW 160          // padded GEMM1 N: 128 h + 8 logits + 24 zero pad
#define LOGIT0 128
#define KSPLIT 2
#define KLEN (DDIM / KSPLIT)   // 1024
#define NT (KLEN / 64)         // 16 K-steps of 64

typedef __attribute__((ext_vector_type(8))) short bf16x8;
typedef __attribute__((ext_vector_type(4))) short short4v;
typedef __attribute__((ext_vector_type(4))) float f32x4;

__device__ __forceinline__ short f2b(float f) {
  unsigned u = __float_as_uint(f);
  u += 0x7fffu + ((u >> 16) & 1u);   // round-to-nearest-even
  return (short)(u >> 16);
}
__device__ __forceinline__ float b2f(short s) {
  return __uint_as_float(((unsigned)(unsigned short)s) << 16);
}

// ---------------- K0: weight prep (fp32 -> bf16, transposed layouts) -------
// WdT[n][k] row-major (UNswizzled; gemm1 reads B straight from L2):
//   n<128 -> down[n>>4][k][n&15]; 128..135 -> rw[n-128][k]; else 0
// UT[d][c]: up[c>>4][c&15][d]  (B-operand N x K for gemm2)
__global__ __launch_bounds__(256) void prep_k(const float* __restrict__ rw,
                                              const float* __restrict__ down,
                                              const float* __restrict__ up,
                                              short* __restrict__ WdT,
                                              short* __restrict__ UT) {
  int i = blockIdx.x * 256 + threadIdx.x;
  const int NWD = NW * DDIM;          // 327680
  const int NUT = DDIM * NC;          // 262144
  if (i < NWD) {
    int n = i / DDIM, k = i % DDIM;
    float v = 0.f;
    if (n < NC)             v = down[((n >> 4) * DDIM + k) * RNK + (n & 15)];
    else if (n < NC + NEXP) v = rw[(n - NC) * DDIM + k];
    WdT[i] = f2b(v);
  } else if (i < NWD + NUT) {
    int u = i - NWD;
    int d = u >> 7, c = u & 127;
    UT[u] = f2b(up[((c >> 4) * RNK + (c & 15)) * DDIM + d]);
  }
}

// ---------------- K1: GEMM1  Hp[ks][16384][160] (bf16) = X @ WdT^T ---------
// Split-K=2, BM=64, BK=64. 4 waves: 2(row)x2(col), each 32 rows x 80 cols.
// A: reg-staged fp32->bf16 into double-buffered LDS (18.4 KB only).
// B: fragments loaded straight from L2-resident WdT into VGPRs (no LDS).
// One barrier per K-step; 4 blocks/CU.
__global__ __launch_bounds__(256, 4) void gemm1_k(const float* __restrict__ X,
                                                  const short* __restrict__ WdT,
                                                  short* __restrict__ Hp) {
  __shared__ short Al[2][64][72];      // 18432 B (+8 pad)
  const int tid = threadIdx.x;
  const int lane = tid & 63;
  const int w = tid >> 6;
  const int gm0 = blockIdx.x * 64;
  const int ks = blockIdx.y;
  const int kb = ks * KLEN;
  const int wr = (w & 1) * 32;         // wave row base
  const int wc = (w >> 1) * 80;        // wave col base (5 frags of 16)
  const int lr = lane & 15;
  const int lk = (lane >> 4) * 8;

  f32x4 acc[2][5];
#pragma unroll
  for (int m = 0; m < 2; ++m)
#pragma unroll
    for (int n = 0; n < 5; ++n) acc[m][n] = (f32x4){0.f, 0.f, 0.f, 0.f};

  float4 aR[4];   // A staging: 64x64 fp32 = 256 thr * 4 * float4

  auto loadA = [&](int k0) {
#pragma unroll
    for (int i2 = 0; i2 < 4; ++i2) {
      int f = tid + 256 * i2;
      int row = f >> 4, c4 = f & 15;
      aR[i2] = *(const float4*)(X + (size_t)(gm0 + row) * DDIM + k0 + c4 * 4);
    }
  };
  auto writeA = [&](int buf) {
#pragma unroll
    for (int i2 = 0; i2 < 4; ++i2) {
      int f = tid + 256 * i2;
      int row = f >> 4, c4 = f & 15;
      short4v v;
      v.x = f2b(aR[i2].x); v.y = f2b(aR[i2].y);
      v.z = f2b(aR[i2].z); v.w = f2b(aR[i2].w);
      *(short4v*)&Al[buf][row][c4 * 4] = v;
    }
  };
  auto compute = [&](int buf, int k0) {
#pragma unroll
    for (int kk2 = 0; kk2 < 2; ++kk2) {
      const int kk = kk2 * 32;
      bf16x8 a[2], b[5];
#pragma unroll
      for (int m = 0; m < 2; ++m)
        a[m] = *(const bf16x8*)&Al[buf][wr + m * 16 + lr][kk + lk];
#pragma unroll
      for (int n = 0; n < 5; ++n)
        b[n] = *(const bf16x8*)(WdT + (size_t)(wc + n * 16 + lr) * DDIM + k0 + kk + lk);
#pragma unroll
      for (int m = 0; m < 2; ++m)
#pragma unroll
        for (int n = 0; n < 5; ++n)
          acc[m][n] = __builtin_amdgcn_mfma_f32_16x16x32_bf16(a[m], b[n], acc[m][n], 0, 0, 0);
    }
  };

  loadA(kb);
  writeA(0);
  __syncthreads();
  for (int t = 0; t < NT; ++t) {
    const int cur = t & 1, nxt = cur ^ 1;
    if (t + 1 < NT) loadA(kb + (t + 1) * 64);
    compute(cur, kb + t * 64);
    if (t + 1 < NT) writeA(nxt);
    __syncthreads();
  }

  short* Hq = Hp + (size_t)ks * MTOK * NW;
  const int cr = (lane >> 4) * 4;
#pragma unroll
  for (int m = 0; m < 2; ++m)
#pragma unroll
    for (int n = 0; n < 5; ++n)
#pragma unroll
      for (int r = 0; r < 4; ++r) {
        int row = gm0 + wr + m * 16 + cr + r;
        int col = wc + n * 16 + lr;
        Hq[(size_t)row * NW + col] = f2b(acc[m][n][r]);
      }
}

// ---------------- K2: routing — sum split-K, top2 softmax, scale -> Hw -----
__global__ __launch_bounds__(256) void route_k(const short* __restrict__ Hp,
                                               short* __restrict__ Hw) {
  __shared__ float wv[64][8];
  const int tid = threadIdx.x;
  const int t0 = blockIdx.x * 64;
  const short* H0 = Hp;
  const short* H1 = Hp + (size_t)MTOK * NW;
  if (tid < 64) {
    int t = t0 + tid;
    uint4 l0 = *(const uint4*)(H0 + (size_t)t * NW + LOGIT0);
    uint4 l1 = *(const uint4*)(H1 + (size_t)t * NW + LOGIT0);
    const short* p0 = (const short*)&l0;
    const short* p1 = (const short*)&l1;
    float b0 = -1e30f, b1 = -1e30f;
    int i0 = 0, i1 = 0;
#pragma unroll
    for (int e = 0; e < 8; ++e) {
      float v = b2f(p0[e]) + b2f(p1[e]);
      if (v > b0) { b1 = b0; i1 = i0; b0 = v; i0 = e; }   // lax.top_k tie-break
      else if (v > b1) { b1 = v; i1 = e; }
    }
    float ex = __expf(b1 - b0);
    float inv = 1.f / (1.f + ex);
#pragma unroll
    for (int e = 0; e < 8; ++e)
      wv[tid][e] = (e == i0) ? inv : ((e == i1) ? ex * inv : 0.f);
  }
  __syncthreads();
  const int t = tid >> 2, q = tid & 3;     // token, col-quarter (32 cols)
  const short* a0 = H0 + (size_t)(t0 + t) * NW + q * 32;
  const short* a1 = H1 + (size_t)(t0 + t) * NW + q * 32;
  short* o = Hw + (size_t)(t0 + t) * NC + q * 32;
#pragma unroll
  for (int j = 0; j < 4; ++j) {
    uint4 v0 = *(const uint4*)(a0 + j * 8);
    uint4 v1 = *(const uint4*)(a1 + j * 8);
    const short* s0 = (const short*)&v0;
    const short* s1 = (const short*)&v1;
    short r[8];
    int cbase = q * 32 + j * 8;
#pragma unroll
    for (int e2 = 0; e2 < 8; ++e2) {
      float h = b2f(s0[e2]) + b2f(s1[e2]);
      r[e2] = f2b(h * wv[t][(cbase + e2) >> 4]);
    }
    *(uint4*)(o + j * 8) = *(uint4*)r;
  }
}

// ---------------- K3: GEMM2 + residual  Out = X + Hw @ U -------------------
// BM=128, BN=64, K=128 single stage. Epilogue transposes acc through each
// wave's PRIVATE LDS slice (== its own A rows, no barrier) for float4 I/O.
__global__ __launch_bounds__(256) void gemm2_k(const short* __restrict__ Hw,
                                               const short* __restrict__ UT,
                                               const float* __restrict__ X,
                                               float* __restrict__ Out) {
  __shared__ short Al[128][136];   // +8 pad, row stride 272B (34816 B)
  __shared__ short Bl[64][136];
  const int tid = threadIdx.x;
  const int lane = tid & 63;
  const int w = tid >> 6;
  const int gm0 = blockIdx.x * 128;
  const int n0 = blockIdx.y * 64;
  const int lr = lane & 15;
  const int lk = (lane >> 4) * 8;

#pragma unroll
  for (int i = 0; i < 8; ++i) {
    int f = tid + 256 * i;         // 128 rows x 16 chunks(16B)
    int row = f >> 4, c8 = f & 15;
    *(uint4*)&Al[row][c8 * 8] = *(const uint4*)(Hw + (size_t)(gm0 + row) * NC + c8 * 8);
  }
#pragma unroll
  for (int i = 0; i < 4; ++i) {
    int f = tid + 256 * i;         // 64 rows x 16 chunks
    int row = f >> 4, c8 = f & 15;
    *(uint4*)&Bl[row][c8 * 8] = *(const uint4*)(UT + (size_t)(n0 + row) * NC + c8 * 8);
  }
  __syncthreads();

  f32x4 acc[2][4];
#pragma unroll
  for (int m = 0; m < 2; ++m)
#pragma unroll
    for (int n = 0; n < 4; ++n) acc[m][n] = (f32x4){0.f, 0.f, 0.f, 0.f};

#pragma unroll
  for (int ks = 0; ks < 4; ++ks) {
    const int kk = ks * 32;
    bf16x8 a[2], b[4];
#pragma unroll
    for (int m = 0; m < 2; ++m) a[m] = *(const bf16x8*)&Al[w * 32 + m * 16 + lr][kk + lk];
#pragma unroll
    for (int n = 0; n < 4; ++n) b[n] = *(const bf16x8*)&Bl[n * 16 + lr][kk + lk];
#pragma unroll
    for (int m = 0; m < 2; ++m)
#pragma unroll
      for (int n = 0; n < 4; ++n)
        acc[m][n] = __builtin_amdgcn_mfma_f32_16x16x32_bf16(a[m], b[n], acc[m][n], 0, 0, 0);
  }

  // Epilogue: wave-private LDS transpose (bytes [w*8704, (w+1)*8704) ==
  // exactly Al rows [w*32, w*32+32), which only this wave read as A-frags).
  float* eps = (float*)&Al[0][0] + w * 2176;   // 32 rows x 68 floats
  const int cr = (lane >> 4) * 4;
#pragma unroll
  for (int m = 0; m < 2; ++m)
#pragma unroll
    for (int n = 0; n < 4; ++n)
#pragma unroll
      for (int r = 0; r < 4; ++r)
        eps[(m * 16 + cr + r) * 68 + n * 16 + lr] = acc[m][n][r];

#pragma unroll
  for (int j = 0; j < 8; ++j) {
    int c = lane + 64 * j;         // 512 float4-chunks: 32 rows x 16
    int rl = c >> 4, c4 = c & 15;
    float4 v = *(const float4*)&eps[rl * 68 + c4 * 4];
    size_t idx = (size_t)(gm0 + w * 32 + rl) * DDIM + n0 + c4 * 4;
    const float4 xv = *(const float4*)(X + idx);
    v.x += xv.x; v.y += xv.y; v.z += xv.z; v.w += xv.w;
    *(float4*)(Out + idx) = v;
  }
}

// ---------------------------------------------------------------------------
extern "C" void kernel_launch(void* const* d_in, const int* in_sizes, int n_in,
                              void* d_out, int out_size, void* d_ws, size_t ws_size,
                              hipStream_t stream) {
  const float* x    = (const float*)d_in[0];
  const float* rw   = (const float*)d_in[1];
  const float* down = (const float*)d_in[2];
  const float* up   = (const float*)d_in[3];
  float* out = (float*)d_out;

  char* ws = (char*)d_ws;
  short* WdT = (short*)ws;                          // 160*2048*2          =   655360 B
  short* UT  = (short*)(ws + 655360);               // 2048*128*2          =   524288 B
  short* Hp  = (short*)(ws + 1179648);              // 2*16384*160*2       = 10485760 B
  short* Hw  = (short*)(ws + 11665408);             // 16384*128*2         =  4194304 B
                                                    // total 15859712 B (proven fit)

  prep_k<<<2304, 256, 0, stream>>>(rw, down, up, WdT, UT);
  gemm1_k<<<dim3(MTOK / 64, KSPLIT), 256, 0, stream>>>(x, WdT, Hp);         // 512 blocks
  route_k<<<MTOK / 64, 256, 0, stream>>>(Hp, Hw);                           // 256 blocks
  gemm2_k<<<dim3(MTOK / 128, DDIM / 64), 256, 0, stream>>>(Hw, UT, x, out); // 4096 blocks
}

// Round 5
// 106.819 us; speedup vs baseline: 1.0282x; 1.0282x over previous
//
#include <hip/hip_runtime.h>
#include <hip/hip_bf16.h>

#define MTOK 16384
#define DDIM 2048
#define NEXP 8
#define RNK 16
#define NC 128          // E*R down-projection columns
#define NW 160          // padded GEMM1 N: 128 h + 8 logits + 24 zero pad
#define LOGIT0 128
#define KSPLIT 2
#define KLEN (DDIM / KSPLIT)   // 1024
#define NT (KLEN / 64)         // 16 K-steps of 64
#define BM1 32                 // gemm1 rows per block

typedef __attribute__((ext_vector_type(8))) short bf16x8;
typedef __attribute__((ext_vector_type(4))) short short4v;
typedef __attribute__((ext_vector_type(4))) float f32x4;

typedef __attribute__((address_space(1))) const void gv_t;
typedef __attribute__((address_space(3))) void lv_t;

__device__ __forceinline__ short f2b(float f) {
  unsigned u = __float_as_uint(f);
  u += 0x7fffu + ((u >> 16) & 1u);   // round-to-nearest-even
  return (short)(u >> 16);
}
__device__ __forceinline__ float b2f(short s) {
  return __uint_as_float(((unsigned)(unsigned short)s) << 16);
}

// ---------------- K0: weight prep (fp32 -> bf16, transposed layouts) -------
// WdT pre-swizzled per 64-elem K-tile: linear position slot s (16B units)
// holds logical slot s^(n&7), so gemm1's linear global_load_lds + swizzled
// ds_read_b128 is bank-conflict-free (T2 via pre-swizzled source, m173).
// Logical WdT[n][k]: n<128 -> down[n>>4][k][n&15]; 128..135 -> rw[n-128][k]; else 0
// UT[d][c]: up[c>>4][c&15][d]  (B-operand N x K for gemm2)
__global__ __launch_bounds__(256) void prep_k(const float* __restrict__ rw,
                                              const float* __restrict__ down,
                                              const float* __restrict__ up,
                                              short* __restrict__ WdT,
                                              short* __restrict__ UT) {
  int i = blockIdx.x * 256 + threadIdx.x;
  const int NWD = NW * DDIM;          // 327680
  const int NUT = DDIM * NC;          // 262144
  if (i < NWD) {
    int n = i / DDIM, k = i % DDIM;
    int s = (k >> 3) & 7;
    int src_k = (k & ~0x3F) | ((s ^ (n & 7)) << 3) | (k & 7);
    float v = 0.f;
    if (n < NC)             v = down[((n >> 4) * DDIM + src_k) * RNK + (n & 15)];
    else if (n < NC + NEXP) v = rw[(n - NC) * DDIM + src_k];
    WdT[i] = f2b(v);
  } else if (i < NWD + NUT) {
    int u = i - NWD;
    int d = u >> 7, c = u & 127;
    UT[u] = f2b(up[((c >> 4) * RNK + (c & 15)) * DDIM + d]);
  }
}

// ---------------- K1: GEMM1  Hp[ks][16384][160] (bf16) = X @ WdT^T ---------
// Split-K=2, BM=32, BK=64. 4 waves: 2(row)x2(col), each 16 rows x 80 cols.
// B: global_load_lds (16B) into linear double-buffered LDS (pre-swizzled src).
// A: reg-staged fp32->bf16 into padded LDS. One barrier per K-step.
// LDS 50176 B -> 3 blocks/CU; grid 1024 blocks.
__global__ __launch_bounds__(256, 3) void gemm1_k(const float* __restrict__ X,
                                                  const short* __restrict__ WdT,
                                                  short* __restrict__ Hp) {
  __shared__ short Al[2][BM1][72];     // 9216 B (+8 pad)
  __shared__ short Bl[2][160 * 64];    // 40960 B, linear for global_load_lds
  const int tid = threadIdx.x;
  const int lane = tid & 63;
  const int w = tid >> 6;
  const int gm0 = blockIdx.x * BM1;
  const int ks = blockIdx.y;
  const int kb = ks * KLEN;
  const int wr = (w & 1) * 16;         // wave row base
  const int wc = (w >> 1) * 80;        // wave col base (5 frags of 16)
  const int lr = lane & 15;
  const int lk = (lane >> 4) * 8;

  f32x4 acc[5];
#pragma unroll
  for (int n = 0; n < 5; ++n) acc[n] = (f32x4){0.f, 0.f, 0.f, 0.f};

  float4 aR[2];   // A staging: 32x64 fp32 = 256 thr * 2 * float4

  auto loadA = [&](int k0) {
#pragma unroll
    for (int i2 = 0; i2 < 2; ++i2) {
      int f = tid + 256 * i2;
      int row = f >> 4, c4 = f & 15;
      aR[i2] = *(const float4*)(X + (size_t)(gm0 + row) * DDIM + k0 + c4 * 4);
    }
  };
  auto issueB = [&](int buf, int k0) {
    // 160x64 bf16 = 1280 x 16B units; 4 waves x 5 calls x 64 lanes
#pragma unroll
    for (int j = 0; j < 5; ++j) {
      int u = (w * 5 + j) * 64 + lane;
      const short* g = WdT + (size_t)(u >> 3) * DDIM + k0 + (u & 7) * 8;
      short* l = &Bl[buf][(w * 5 + j) * 512];   // wave-uniform base
      __builtin_amdgcn_global_load_lds((gv_t*)g, (lv_t*)l, 16, 0, 0);
    }
  };
  auto writeA = [&](int buf) {
#pragma unroll
    for (int i2 = 0; i2 < 2; ++i2) {
      int f = tid + 256 * i2;
      int row = f >> 4, c4 = f & 15;
      short4v v;
      v.x = f2b(aR[i2].x); v.y = f2b(aR[i2].y);
      v.z = f2b(aR[i2].z); v.w = f2b(aR[i2].w);
      *(short4v*)&Al[buf][row][c4 * 4] = v;
    }
  };
  auto compute = [&](int buf) {
#pragma unroll
    for (int kk2 = 0; kk2 < 2; ++kk2) {
      const int kk = kk2 * 32;
      bf16x8 a = *(const bf16x8*)&Al[buf][wr + lr][kk + lk];
      bf16x8 b[5];
#pragma unroll
      for (int n = 0; n < 5; ++n) {
        int row = wc + n * 16 + lr;
        int sl = ((kk >> 3) + (lane >> 4)) ^ (row & 7);   // swizzled 16B slot
        b[n] = *(const bf16x8*)&Bl[buf][row * 64 + sl * 8];
      }
#pragma unroll
      for (int n = 0; n < 5; ++n)
        acc[n] = __builtin_amdgcn_mfma_f32_16x16x32_bf16(a, b[n], acc[n], 0, 0, 0);
    }
  };

  loadA(kb);
  issueB(0, kb);
  writeA(0);
  __syncthreads();
  for (int t = 0; t < NT; ++t) {
    const int cur = t & 1, nxt = cur ^ 1;
    if (t + 1 < NT) {
      loadA(kb + (t + 1) * 64);
      issueB(nxt, kb + (t + 1) * 64);
    }
    compute(cur);
    if (t + 1 < NT) writeA(nxt);
    __syncthreads();
  }

  short* Hq = Hp + (size_t)ks * MTOK * NW;
  const int cr = (lane >> 4) * 4;
#pragma unroll
  for (int n = 0; n < 5; ++n)
#pragma unroll
    for (int r = 0; r < 4; ++r) {
      int row = gm0 + wr + cr + r;
      int col = wc + n * 16 + lr;
      Hq[(size_t)row * NW + col] = f2b(acc[n][r]);
    }
}

// ---------------- K2: routing — sum split-K, top2 softmax, scale -> Hw -----
__global__ __launch_bounds__(256) void route_k(const short* __restrict__ Hp,
                                               short* __restrict__ Hw) {
  __shared__ float wv[64][8];
  const int tid = threadIdx.x;
  const int t0 = blockIdx.x * 64;
  const short* H0 = Hp;
  const short* H1 = Hp + (size_t)MTOK * NW;
  if (tid < 64) {
    int t = t0 + tid;
    uint4 l0 = *(const uint4*)(H0 + (size_t)t * NW + LOGIT0);
    uint4 l1 = *(const uint4*)(H1 + (size_t)t * NW + LOGIT0);
    const short* p0 = (const short*)&l0;
    const short* p1 = (const short*)&l1;
    float b0 = -1e30f, b1 = -1e30f;
    int i0 = 0, i1 = 0;
#pragma unroll
    for (int e = 0; e < 8; ++e) {
      float v = b2f(p0[e]) + b2f(p1[e]);
      if (v > b0) { b1 = b0; i1 = i0; b0 = v; i0 = e; }   // lax.top_k tie-break
      else if (v > b1) { b1 = v; i1 = e; }
    }
    float ex = __expf(b1 - b0);
    float inv = 1.f / (1.f + ex);
#pragma unroll
    for (int e = 0; e < 8; ++e)
      wv[tid][e] = (e == i0) ? inv : ((e == i1) ? ex * inv : 0.f);
  }
  __syncthreads();
  const int t = tid >> 2, q = tid & 3;     // token, col-quarter (32 cols)
  const short* a0 = H0 + (size_t)(t0 + t) * NW + q * 32;
  const short* a1 = H1 + (size_t)(t0 + t) * NW + q * 32;
  short* o = Hw + (size_t)(t0 + t) * NC + q * 32;
#pragma unroll
  for (int j = 0; j < 4; ++j) {
    uint4 v0 = *(const uint4*)(a0 + j * 8);
    uint4 v1 = *(const uint4*)(a1 + j * 8);
    const short* s0 = (const short*)&v0;
    const short* s1 = (const short*)&v1;
    short r[8];
    int cbase = q * 32 + j * 8;
#pragma unroll
    for (int e2 = 0; e2 < 8; ++e2) {
      float h = b2f(s0[e2]) + b2f(s1[e2]);
      r[e2] = f2b(h * wv[t][(cbase + e2) >> 4]);
    }
    *(uint4*)(o + j * 8) = *(uint4*)r;
  }
}

// ---------------- K3: GEMM2 + residual  Out = X + Hw @ U -------------------
// BM=128, BN=64, K=128 single stage. Epilogue transposes acc through each
// wave's PRIVATE LDS slice (== its own A rows, no barrier) for float4 I/O.
__global__ __launch_bounds__(256) void gemm2_k(const short* __restrict__ Hw,
                                               const short* __restrict__ UT,
                                               const float* __restrict__ X,
                                               float* __restrict__ Out) {
  __shared__ short Al[128][136];   // +8 pad, row stride 272B (34816 B)
  __shared__ short Bl[64][136];
  const int tid = threadIdx.x;
  const int lane = tid & 63;
  const int w = tid >> 6;
  const int gm0 = blockIdx.x * 128;
  const int n0 = blockIdx.y * 64;
  const int lr = lane & 15;
  const int lk = (lane >> 4) * 8;

#pragma unroll
  for (int i = 0; i < 8; ++i) {
    int f = tid + 256 * i;         // 128 rows x 16 chunks(16B)
    int row = f >> 4, c8 = f & 15;
    *(uint4*)&Al[row][c8 * 8] = *(const uint4*)(Hw + (size_t)(gm0 + row) * NC + c8 * 8);
  }
#pragma unroll
  for (int i = 0; i < 4; ++i) {
    int f = tid + 256 * i;         // 64 rows x 16 chunks
    int row = f >> 4, c8 = f & 15;
    *(uint4*)&Bl[row][c8 * 8] = *(const uint4*)(UT + (size_t)(n0 + row) * NC + c8 * 8);
  }
  __syncthreads();

  f32x4 acc[2][4];
#pragma unroll
  for (int m = 0; m < 2; ++m)
#pragma unroll
    for (int n = 0; n < 4; ++n) acc[m][n] = (f32x4){0.f, 0.f, 0.f, 0.f};

#pragma unroll
  for (int ks = 0; ks < 4; ++ks) {
    const int kk = ks * 32;
    bf16x8 a[2], b[4];
#pragma unroll
    for (int m = 0; m < 2; ++m) a[m] = *(const bf16x8*)&Al[w * 32 + m * 16 + lr][kk + lk];
#pragma unroll
    for (int n = 0; n < 4; ++n) b[n] = *(const bf16x8*)&Bl[n * 16 + lr][kk + lk];
#pragma unroll
    for (int m = 0; m < 2; ++m)
#pragma unroll
      for (int n = 0; n < 4; ++n)
        acc[m][n] = __builtin_amdgcn_mfma_f32_16x16x32_bf16(a[m], b[n], acc[m][n], 0, 0, 0);
  }

  // Epilogue: wave-private LDS transpose (bytes [w*8704, (w+1)*8704) ==
  // exactly Al rows [w*32, w*32+32), which only this wave read as A-frags).
  float* eps = (float*)&Al[0][0] + w * 2176;   // 32 rows x 68 floats
  const int cr = (lane >> 4) * 4;
#pragma unroll
  for (int m = 0; m < 2; ++m)
#pragma unroll
    for (int n = 0; n < 4; ++n)
#pragma unroll
      for (int r = 0; r < 4; ++r)
        eps[(m * 16 + cr + r) * 68 + n * 16 + lr] = acc[m][n][r];

#pragma unroll
  for (int j = 0; j < 8; ++j) {
    int c = lane + 64 * j;         // 512 float4-chunks: 32 rows x 16
    int rl = c >> 4, c4 = c & 15;
    float4 v = *(const float4*)&eps[rl * 68 + c4 * 4];
    size_t idx = (size_t)(gm0 + w * 32 + rl) * DDIM + n0 + c4 * 4;
    const float4 xv = *(const float4*)(X + idx);
    v.x += xv.x; v.y += xv.y; v.z += xv.z; v.w += xv.w;
    *(float4*)(Out + idx) = v;
  }
}

// ---------------------------------------------------------------------------
extern "C" void kernel_launch(void* const* d_in, const int* in_sizes, int n_in,
                              void* d_out, int out_size, void* d_ws, size_t ws_size,
                              hipStream_t stream) {
  const float* x    = (const float*)d_in[0];
  const float* rw   = (const float*)d_in[1];
  const float* down = (const float*)d_in[2];
  const float* up   = (const float*)d_in[3];
  float* out = (float*)d_out;

  char* ws = (char*)d_ws;
  short* WdT = (short*)ws;                          // 160*2048*2          =   655360 B
  short* UT  = (short*)(ws + 655360);               // 2048*128*2          =   524288 B
  short* Hp  = (short*)(ws + 1179648);              // 2*16384*160*2       = 10485760 B
  short* Hw  = (short*)(ws + 11665408);             // 16384*128*2         =  4194304 B
                                                    // total 15859712 B (proven fit)

  prep_k<<<2304, 256, 0, stream>>>(rw, down, up, WdT, UT);
  gemm1_k<<<dim3(MTOK / BM1, KSPLIT), 256, 0, stream>>>(x, WdT, Hp);        // 1024 blocks
  route_k<<<MTOK / 64, 256, 0, stream>>>(Hp, Hw);                           // 256 blocks
  gemm2_k<<<dim3(MTOK / 128, DDIM / 64), 256, 0, stream>>>(Hw, UT, x, out); // 4096 blocks
}

// Round 6
// 87.001 us; speedup vs baseline: 1.2624x; 1.2278x over previous
//
#include <hip/hip_runtime.h>
#include <hip/hip_bf16.h>

#define MTOK 16384
#define DDIM 2048
#define NEXP 8
#define RNK 16
#define NC 128          // E*R down-projection columns
#define NW 160          // padded GEMM1 N: 128 h + 8 logits + 24 zero pad
#define LOGIT0 128
#define KSPLIT 2
#define KLEN (DDIM / KSPLIT)   // 1024
#define NT (KLEN / 64)         // 16 K-steps of 64

typedef __attribute__((ext_vector_type(8))) short bf16x8;
typedef __attribute__((ext_vector_type(4))) short short4v;
typedef __attribute__((ext_vector_type(4))) float f32x4;

typedef __attribute__((address_space(1))) const void gv_t;
typedef __attribute__((address_space(3))) void lv_t;

__device__ __forceinline__ short f2b(float f) {
  unsigned u = __float_as_uint(f);
  u += 0x7fffu + ((u >> 16) & 1u);   // round-to-nearest-even
  return (short)(u >> 16);
}
__device__ __forceinline__ float b2f(short s) {
  return __uint_as_float(((unsigned)(unsigned short)s) << 16);
}

// ---------------- K0: weight prep (fp32 -> bf16, transposed layouts) -------
// WdT pre-swizzled per 64-elem K-tile: linear 16B-slot s holds logical slot
// s^(n&7) -> linear global_load_lds + swizzled ds_read_b128 is conflict-free.
// Logical WdT[n][k]: n<128 -> down[n>>4][k][n&15]; 128..135 -> rw[n-128][k]; else 0
// UT[d][c]: up[c>>4][c&15][d]
__global__ __launch_bounds__(256) void prep_k(const float* __restrict__ rw,
                                              const float* __restrict__ down,
                                              const float* __restrict__ up,
                                              short* __restrict__ WdT,
                                              short* __restrict__ UT) {
  int i = blockIdx.x * 256 + threadIdx.x;
  const int NWD = NW * DDIM;          // 327680
  const int NUT = DDIM * NC;          // 262144
  if (i < NWD) {
    int n = i / DDIM, k = i % DDIM;
    int s = (k >> 3) & 7;
    int src_k = (k & ~0x3F) | ((s ^ (n & 7)) << 3) | (k & 7);
    float v = 0.f;
    if (n < NC)             v = down[((n >> 4) * DDIM + src_k) * RNK + (n & 15)];
    else if (n < NC + NEXP) v = rw[(n - NC) * DDIM + src_k];
    WdT[i] = f2b(v);
  } else if (i < NWD + NUT) {
    int u = i - NWD;
    int d = u >> 7, c = u & 127;
    UT[u] = f2b(up[((c >> 4) * RNK + (c & 15)) * DDIM + d]);
  }
}

// ---------------- K1: GEMM1  Hp[ks][16384][160] (bf16) = X @ WdT^T ---------
// Split-K=2, BM=64, BK=64. 4 waves: 2(row)x2(col), each 32 rows x 80 cols.
// Counted-vmcnt pipeline (T3+T4): A and B both issued 2 K-steps ahead;
// steady-state s_waitcnt vmcnt(7) (A(t+1)2+B(t+1)5 retire), never 0.
// Two raw barriers per step, no vmcnt(0) drain. Full unroll -> static bufs.
__global__ __launch_bounds__(256, 4) void gemm1_k(const float* __restrict__ X,
                                                  const short* __restrict__ WdT,
                                                  short* __restrict__ Hp) {
  __shared__ short Al[2][64][72];      // 18432 B (+8 pad)
  __shared__ short Bl[2][160 * 64];    // 40960 B, linear for global_load_lds
  const int tid = threadIdx.x;
  const int lane = tid & 63;
  const int w = tid >> 6;
  const int gm0 = blockIdx.x * 64;
  const int ks = blockIdx.y;
  const int kb = ks * KLEN;
  const int wr = (w & 1) * 32;         // wave row base
  const int wc = (w >> 1) * 80;        // wave col base (5 frags of 16)
  const int lr = lane & 15;
  const int lk = (lane >> 4) * 8;

  f32x4 acc[2][5];
#pragma unroll
  for (int m = 0; m < 2; ++m)
#pragma unroll
    for (int n = 0; n < 5; ++n) acc[m][n] = (f32x4){0.f, 0.f, 0.f, 0.f};

  float4 aR[2][4];   // two A staging sets (2 K-steps in flight)

  auto loadA = [&](int k0, int s) {
#pragma unroll
    for (int i2 = 0; i2 < 4; ++i2) {
      int f = tid + 256 * i2;
      int row = f >> 4, c4 = f & 15;
      aR[s][i2] = *(const float4*)(X + (size_t)(gm0 + row) * DDIM + k0 + c4 * 4);
    }
  };
  auto issueB = [&](int buf, int k0) {
    // 160x64 bf16 = 1280 x 16B units; 4 waves x 5 calls x 64 lanes
#pragma unroll
    for (int j = 0; j < 5; ++j) {
      int u = (w * 5 + j) * 64 + lane;
      const short* g = WdT + (size_t)(u >> 3) * DDIM + k0 + (u & 7) * 8;
      short* l = &Bl[buf][(w * 5 + j) * 512];   // wave-uniform base
      __builtin_amdgcn_global_load_lds((gv_t*)g, (lv_t*)l, 16, 0, 0);
    }
  };
  auto writeA = [&](int buf, int s) {
#pragma unroll
    for (int i2 = 0; i2 < 4; ++i2) {
      int f = tid + 256 * i2;
      int row = f >> 4, c4 = f & 15;
      short4v v;
      v.x = f2b(aR[s][i2].x); v.y = f2b(aR[s][i2].y);
      v.z = f2b(aR[s][i2].z); v.w = f2b(aR[s][i2].w);
      *(short4v*)&Al[buf][row][c4 * 4] = v;
    }
  };
  auto compute = [&](int buf) {
#pragma unroll
    for (int kk2 = 0; kk2 < 2; ++kk2) {
      const int kk = kk2 * 32;
      bf16x8 a[2], b[5];
#pragma unroll
      for (int m = 0; m < 2; ++m)
        a[m] = *(const bf16x8*)&Al[buf][wr + m * 16 + lr][kk + lk];
#pragma unroll
      for (int n = 0; n < 5; ++n) {
        int row = wc + n * 16 + lr;
        int sl = ((kk >> 3) + (lane >> 4)) ^ (row & 7);   // swizzled 16B slot
        b[n] = *(const bf16x8*)&Bl[buf][row * 64 + sl * 8];
      }
#pragma unroll
      for (int m = 0; m < 2; ++m)
#pragma unroll
        for (int n = 0; n < 5; ++n)
          acc[m][n] = __builtin_amdgcn_mfma_f32_16x16x32_bf16(a[m], b[n], acc[m][n], 0, 0, 0);
    }
  };

  // ---- prologue: establish steady state (outstanding = A(1)2 + B(1)5) ----
  loadA(kb, 0);            // A(0): 2 loads
  issueB(0, kb);           // B(0): 5 gload_lds
  loadA(kb + 64, 1);       // A(1): 2
  issueB(1, kb + 64);      // B(1): 5   -> 14 outstanding
  asm volatile("s_waitcnt vmcnt(12)" ::: "memory");   // A(0) retired
  __builtin_amdgcn_sched_barrier(0);
  writeA(0, 0);
  asm volatile("s_waitcnt vmcnt(7)" ::: "memory");    // B(0) retired
  asm volatile("s_waitcnt lgkmcnt(0)" ::: "memory");
  __builtin_amdgcn_sched_barrier(0);
  __builtin_amdgcn_s_barrier();

  // ---- main loop: fully unrolled, all buffer indices static ----
#pragma unroll
  for (int t = 0; t < NT; ++t) {
    if (t + 2 < NT) loadA(kb + (t + 2) * 64, t & 1);  // A(t+2) into free set
    compute(t & 1);
    asm volatile("s_waitcnt lgkmcnt(0)" ::: "memory");
    __builtin_amdgcn_s_barrier();                     // all waves done with buf t&1
    __builtin_amdgcn_sched_barrier(0);
    if (t + 2 < NT) issueB(t & 1, kb + (t + 2) * 64); // B(t+2) into just-freed buf
    if (t + 1 < NT) {
      if (t + 2 < NT)
        asm volatile("s_waitcnt vmcnt(7)" ::: "memory");  // retire A(t+1),B(t+1)
      else
        asm volatile("s_waitcnt vmcnt(0)" ::: "memory");  // tail: nothing newer in flight
      __builtin_amdgcn_sched_barrier(0);
      writeA((t + 1) & 1, (t + 1) & 1);
      asm volatile("s_waitcnt lgkmcnt(0)" ::: "memory");
      __builtin_amdgcn_sched_barrier(0);
    }
    __builtin_amdgcn_s_barrier();                     // publish A(t+1), B(t+1)
  }

  short* Hq = Hp + (size_t)ks * MTOK * NW;
  const int cr = (lane >> 4) * 4;
#pragma unroll
  for (int m = 0; m < 2; ++m)
#pragma unroll
    for (int n = 0; n < 5; ++n)
#pragma unroll
      for (int r = 0; r < 4; ++r) {
        int row = gm0 + wr + m * 16 + cr + r;
        int col = wc + n * 16 + lr;
        Hq[(size_t)row * NW + col] = f2b(acc[m][n][r]);
      }
}

// ---------------- K2: routing — sum split-K, top2 softmax, scale -> Hw -----
__global__ __launch_bounds__(256) void route_k(const short* __restrict__ Hp,
                                               short* __restrict__ Hw) {
  __shared__ float wv[64][8];
  const int tid = threadIdx.x;
  const int t0 = blockIdx.x * 64;
  const short* H0 = Hp;
  const short* H1 = Hp + (size_t)MTOK * NW;
  if (tid < 64) {
    int t = t0 + tid;
    uint4 l0 = *(const uint4*)(H0 + (size_t)t * NW + LOGIT0);
    uint4 l1 = *(const uint4*)(H1 + (size_t)t * NW + LOGIT0);
    const short* p0 = (const short*)&l0;
    const short* p1 = (const short*)&l1;
    float b0 = -1e30f, b1 = -1e30f;
    int i0 = 0, i1 = 0;
#pragma unroll
    for (int e = 0; e < 8; ++e) {
      float v = b2f(p0[e]) + b2f(p1[e]);
      if (v > b0) { b1 = b0; i1 = i0; b0 = v; i0 = e; }   // lax.top_k tie-break
      else if (v > b1) { b1 = v; i1 = e; }
    }
    float ex = __expf(b1 - b0);
    float inv = 1.f / (1.f + ex);
#pragma unroll
    for (int e = 0; e < 8; ++e)
      wv[tid][e] = (e == i0) ? inv : ((e == i1) ? ex * inv : 0.f);
  }
  __syncthreads();
  const int t = tid >> 2, q = tid & 3;     // token, col-quarter (32 cols)
  const short* a0 = H0 + (size_t)(t0 + t) * NW + q * 32;
  const short* a1 = H1 + (size_t)(t0 + t) * NW + q * 32;
  short* o = Hw + (size_t)(t0 + t) * NC + q * 32;
#pragma unroll
  for (int j = 0; j < 4; ++j) {
    uint4 v0 = *(const uint4*)(a0 + j * 8);
    uint4 v1 = *(const uint4*)(a1 + j * 8);
    const short* s0 = (const short*)&v0;
    const short* s1 = (const short*)&v1;
    short r[8];
    int cbase = q * 32 + j * 8;
#pragma unroll
    for (int e2 = 0; e2 < 8; ++e2) {
      float h = b2f(s0[e2]) + b2f(s1[e2]);
      r[e2] = f2b(h * wv[t][(cbase + e2) >> 4]);
    }
    *(uint4*)(o + j * 8) = *(uint4*)r;
  }
}

// ---------------- K3: GEMM2 + residual  Out = X + Hw @ U -------------------
// BM=128, BN=64, K=128 single stage. Epilogue transposes acc through each
// wave's PRIVATE LDS slice (== its own A rows, no barrier) for float4 I/O.
__global__ __launch_bounds__(256) void gemm2_k(const short* __restrict__ Hw,
                                               const short* __restrict__ UT,
                                               const float* __restrict__ X,
                                               float* __restrict__ Out) {
  __shared__ short Al[128][136];   // +8 pad, row stride 272B (34816 B)
  __shared__ short Bl[64][136];
  const int tid = threadIdx.x;
  const int lane = tid & 63;
  const int w = tid >> 6;
  const int gm0 = blockIdx.x * 128;
  const int n0 = blockIdx.y * 64;
  const int lr = lane & 15;
  const int lk = (lane >> 4) * 8;

#pragma unroll
  for (int i = 0; i < 8; ++i) {
    int f = tid + 256 * i;         // 128 rows x 16 chunks(16B)
    int row = f >> 4, c8 = f & 15;
    *(uint4*)&Al[row][c8 * 8] = *(const uint4*)(Hw + (size_t)(gm0 + row) * NC + c8 * 8);
  }
#pragma unroll
  for (int i = 0; i < 4; ++i) {
    int f = tid + 256 * i;         // 64 rows x 16 chunks
    int row = f >> 4, c8 = f & 15;
    *(uint4*)&Bl[row][c8 * 8] = *(const uint4*)(UT + (size_t)(n0 + row) * NC + c8 * 8);
  }
  __syncthreads();

  f32x4 acc[2][4];
#pragma unroll
  for (int m = 0; m < 2; ++m)
#pragma unroll
    for (int n = 0; n < 4; ++n) acc[m][n] = (f32x4){0.f, 0.f, 0.f, 0.f};

#pragma unroll
  for (int ks = 0; ks < 4; ++ks) {
    const int kk = ks * 32;
    bf16x8 a[2], b[4];
#pragma unroll
    for (int m = 0; m < 2; ++m) a[m] = *(const bf16x8*)&Al[w * 32 + m * 16 + lr][kk + lk];
#pragma unroll
    for (int n = 0; n < 4; ++n) b[n] = *(const bf16x8*)&Bl[n * 16 + lr][kk + lk];
#pragma unroll
    for (int m = 0; m < 2; ++m)
#pragma unroll
      for (int n = 0; n < 4; ++n)
        acc[m][n] = __builtin_amdgcn_mfma_f32_16x16x32_bf16(a[m], b[n], acc[m][n], 0, 0, 0);
  }

  // Epilogue: wave-private LDS transpose (bytes [w*8704, (w+1)*8704) ==
  // exactly Al rows [w*32, w*32+32), which only this wave read as A-frags).
  float* eps = (float*)&Al[0][0] + w * 2176;   // 32 rows x 68 floats
  const int cr = (lane >> 4) * 4;
#pragma unroll
  for (int m = 0; m < 2; ++m)
#pragma unroll
    for (int n = 0; n < 4; ++n)
#pragma unroll
      for (int r = 0; r < 4; ++r)
        eps[(m * 16 + cr + r) * 68 + n * 16 + lr] = acc[m][n][r];

#pragma unroll
  for (int j = 0; j < 8; ++j) {
    int c = lane + 64 * j;         // 512 float4-chunks: 32 rows x 16
    int rl = c >> 4, c4 = c & 15;
    float4 v = *(const float4*)&eps[rl * 68 + c4 * 4];
    size_t idx = (size_t)(gm0 + w * 32 + rl) * DDIM + n0 + c4 * 4;
    const float4 xv = *(const float4*)(X + idx);
    v.x += xv.x; v.y += xv.y; v.z += xv.z; v.w += xv.w;
    *(float4*)(Out + idx) = v;
  }
}

// ---------------------------------------------------------------------------
extern "C" void kernel_launch(void* const* d_in, const int* in_sizes, int n_in,
                              void* d_out, int out_size, void* d_ws, size_t ws_size,
                              hipStream_t stream) {
  const float* x    = (const float*)d_in[0];
  const float* rw   = (const float*)d_in[1];
  const float* down = (const float*)d_in[2];
  const float* up   = (const float*)d_in[3];
  float* out = (float*)d_out;

  char* ws = (char*)d_ws;
  short* WdT = (short*)ws;                          // 160*2048*2          =   655360 B
  short* UT  = (short*)(ws + 655360);               // 2048*128*2          =   524288 B
  short* Hp  = (short*)(ws + 1179648);              // 2*16384*160*2       = 10485760 B
  short* Hw  = (short*)(ws + 11665408);             // 16384*128*2         =  4194304 B
                                                    // total 15859712 B (proven fit)

  prep_k<<<2304, 256, 0, stream>>>(rw, down, up, WdT, UT);
  gemm1_k<<<dim3(MTOK / 64, KSPLIT), 256, 0, stream>>>(x, WdT, Hp);         // 512 blocks
  route_k<<<MTOK / 64, 256, 0, stream>>>(Hp, Hw);                           // 256 blocks
  gemm2_k<<<dim3(MTOK / 128, DDIM / 64), 256, 0, stream>>>(Hw, UT, x, out); // 4096 blocks
}